// Round 1
// baseline (522.252 us; speedup 1.0000x reference)
//
#include <hip/hip_runtime.h>

typedef __attribute__((ext_vector_type(8))) short short8_t;  // 8 bf16 (4 VGPRs)
typedef __attribute__((ext_vector_type(4))) float float4_t;  // MFMA C/D
typedef unsigned short u16;
typedef unsigned int u32;
typedef unsigned long long u64;

// ---------- helpers ----------
__device__ inline u16 f2bf(float x) {
  union { float f; u32 u; } v; v.f = x;
  u32 r = v.u + 0x7FFFu + ((v.u >> 16) & 1u);  // round-to-nearest-even
  return (u16)(r >> 16);
}
__device__ inline u32 packbf(float a, float b) {
  return (u32)f2bf(a) | ((u32)f2bf(b) << 16);
}

// ---------- X fp32 -> bf16 ----------
__global__ __launch_bounds__(256) void convert_x(const float* __restrict__ X, u16* __restrict__ Xb) {
  int i = blockIdx.x * 256 + threadIdx.x;   // one float4 per thread
  float4_t x = ((const float4_t*)X)[i];
  union { u32 u[2]; u64 ll; } o;
  o.u[0] = packbf(x[0], x[1]);
  o.u[1] = packbf(x[2], x[3]);
  ((u64*)Xb)[i] = o.ll;
}

// ---------- W [K,N] fp32 -> WT [N,K] bf16 (1024x1024) ----------
__global__ __launch_bounds__(256) void transpose_w(const float* __restrict__ W, u16* __restrict__ WT) {
  __shared__ float t[32][33];
  int tx = threadIdx.x, ty = threadIdx.y;          // 32 x 8
  int r0 = blockIdx.y * 32, c0 = blockIdx.x * 32;  // r0: k, c0: n
  #pragma unroll
  for (int i = 0; i < 4; ++i)
    t[ty + i * 8][tx] = W[(r0 + ty + i * 8) * 1024 + c0 + tx];
  __syncthreads();
  #pragma unroll
  for (int i = 0; i < 4; ++i)
    WT[(c0 + ty + i * 8) * 1024 + r0 + tx] = f2bf(t[tx][ty + i * 8]);
}

// ---------- GEMM: C = A[4096,1024] * W (BT = W^T [1024,1024]) + bias ----------
// mode 0: Q -> [B,H,S,64] bf16, scaled by 0.125
// mode 1: K -> [B,H,S,64] bf16
// mode 2: V -> [B,H,64,S] bf16 (transposed)
// mode 3: O -> [4096,1024] fp32 (d_out)
__global__ __launch_bounds__(256) void gemm_bf16(const u16* __restrict__ A, const u16* __restrict__ BT,
                                                 const float* __restrict__ bias, void* __restrict__ outp,
                                                 int mode) {
  int m0 = blockIdx.x * 128, n0 = blockIdx.y * 64;
  int lane = threadIdx.x & 63, wave = threadIdx.x >> 6;
  int quad = lane >> 4, c = lane & 15;
  int wm = wave >> 1, wn = wave & 1;
  int mrow = m0 + wm * 64, ncol = n0 + wn * 32;
  const u16* pa = A + (mrow + c) * 1024 + quad * 8;
  const u16* pb = BT + (ncol + c) * 1024 + quad * 8;
  float4_t acc[4][2] = {};
  #pragma unroll 2
  for (int k0 = 0; k0 < 1024; k0 += 32) {
    short8_t af[4], bfr[2];
    #pragma unroll
    for (int i = 0; i < 4; ++i) af[i] = *(const short8_t*)(pa + i * 16384 + k0);
    #pragma unroll
    for (int j = 0; j < 2; ++j) bfr[j] = *(const short8_t*)(pb + j * 16384 + k0);
    #pragma unroll
    for (int i = 0; i < 4; ++i)
      #pragma unroll
      for (int j = 0; j < 2; ++j)
        acc[i][j] = __builtin_amdgcn_mfma_f32_16x16x32_bf16(af[i], bfr[j], acc[i][j], 0, 0, 0);
  }
  #pragma unroll
  for (int i = 0; i < 4; ++i) {
    #pragma unroll
    for (int j = 0; j < 2; ++j) {
      int colb = ncol + j * 16 + c;
      float bv = bias[colb];
      int rowb = mrow + i * 16 + quad * 4;  // rows rowb..rowb+3
      if (mode == 2) {
        int b = rowb >> 11, s = rowb & 2047;
        int h = colb >> 6, d = colb & 63;
        u16* o = (u16*)outp + (((b * 16 + h) * 64 + d) * 2048 + s);
        union { u32 u[2]; u64 ll; } ov;
        ov.u[0] = packbf(acc[i][j][0] + bv, acc[i][j][1] + bv);
        ov.u[1] = packbf(acc[i][j][2] + bv, acc[i][j][3] + bv);
        *(u64*)o = ov.ll;
      } else if (mode == 3) {
        float* o = (float*)outp;
        #pragma unroll
        for (int r = 0; r < 4; ++r)
          o[(rowb + r) * 1024 + colb] = acc[i][j][r] + bv;
      } else {
        float sc = (mode == 0) ? 0.125f : 1.0f;
        u16* o = (u16*)outp;
        #pragma unroll
        for (int r = 0; r < 4; ++r) {
          int row = rowb + r;
          int b = row >> 11, s = row & 2047;
          int h = colb >> 6, d = colb & 63;
          o[(((b * 16 + h) * 2048 + s) << 6) + d] = f2bf((acc[i][j][r] + bv) * sc);
        }
      }
    }
  }
}

// ---------- flash attention: S^T = K Q^T, online softmax, ctx^T = V^T P^T ----------
// Q,K: [B,H,S,64] bf16 (Q pre-scaled by 1/8); VT: [B,H,64,S] bf16
// ctx out: [B,S,1024] bf16
__global__ __launch_bounds__(256) void attn_kernel(const u16* __restrict__ Q, const u16* __restrict__ K,
                                                   const u16* __restrict__ VT, const float* __restrict__ mask,
                                                   u16* __restrict__ ctx) {
  const float LOG2E = 1.4426950408889634f;
  int wid = blockIdx.x * 4 + (threadIdx.x >> 6);  // 4096 waves total
  int lane = threadIdx.x & 63;
  int quad = lane >> 4, c = lane & 15;
  int b = wid >> 11;
  int rem = wid & 2047;
  int h = rem >> 7;
  int qblk = rem & 127;
  int q0 = qblk << 4;
  const u16* Qp = Q + (((b * 16 + h) * 2048 + q0) << 6);
  const u16* Kp = K + ((size_t)(b * 16 + h) << 17);
  const u16* Vp = VT + ((size_t)(b * 16 + h) << 17);
  const float* mp = mask + (b << 11);

  // Q^T B-operand fragments: lane holds Q[q0+c][quad*8+j (+32)]
  short8_t qf0 = *(const short8_t*)(Qp + c * 64 + quad * 8);
  short8_t qf1 = *(const short8_t*)(Qp + c * 64 + 32 + quad * 8);

  float4_t O0 = {}, O1 = {}, O2 = {}, O3 = {};  // ctx^T, d-blocks of 16
  float m = -1e30f, l = 0.0f;
  int qg = q0 + c;
  int tmax = (q0 + 15) >> 5;
  for (int t = 0; t <= tmax; ++t) {
    int kbase = t << 5;
    // --- S^T = K_tile @ Q^T : D[kpos][q], kpos = quad*4+r (+16*blk), q = c
    float4_t s0 = {}, s1 = {};
    {
      const u16* kp = Kp + (kbase + c) * 64 + quad * 8;
      short8_t ka0 = *(const short8_t*)(kp);
      short8_t ka1 = *(const short8_t*)(kp + 32);
      s0 = __builtin_amdgcn_mfma_f32_16x16x32_bf16(ka0, qf0, s0, 0, 0, 0);
      s0 = __builtin_amdgcn_mfma_f32_16x16x32_bf16(ka1, qf1, s0, 0, 0, 0);
      kp += 16 * 64;
      short8_t kb0 = *(const short8_t*)(kp);
      short8_t kb1 = *(const short8_t*)(kp + 32);
      s1 = __builtin_amdgcn_mfma_f32_16x16x32_bf16(kb0, qf0, s1, 0, 0, 0);
      s1 = __builtin_amdgcn_mfma_f32_16x16x32_bf16(kb1, qf1, s1, 0, 0, 0);
    }
    float sv[8];
    #pragma unroll
    for (int r = 0; r < 4; ++r) { sv[r] = s0[r]; sv[4 + r] = s1[r]; }
    // --- masks + online softmax (per-lane state: column q = q0+c)
    float smax = -1e30f;
    #pragma unroll
    for (int e = 0; e < 8; ++e) {
      int kpos = kbase + ((e >> 2) << 4) + quad * 4 + (e & 3);
      float sc = sv[e];
      sc += (1.0f - mp[kpos]) * -10000.0f;     // padding mask
      sc += (kpos > qg) ? -1e10f : 0.0f;       // causal mask
      sv[e] = sc;
      smax = fmaxf(smax, sc);
    }
    smax = fmaxf(smax, __shfl_xor(smax, 16));
    smax = fmaxf(smax, __shfl_xor(smax, 32));
    float mn = fmaxf(m, smax);
    float alpha = exp2f((m - mn) * LOG2E);
    float psum = 0.0f;
    #pragma unroll
    for (int e = 0; e < 8; ++e) {
      float p = exp2f((sv[e] - mn) * LOG2E);
      sv[e] = p;
      psum += p;
    }
    psum += __shfl_xor(psum, 16);
    psum += __shfl_xor(psum, 32);
    l = l * alpha + psum;
    m = mn;
    O0 *= alpha; O1 *= alpha; O2 *= alpha; O3 *= alpha;
    // --- P^T (C-layout) -> B-operand layout via packed-bf16 shuffles
    u32 pk[2][2];
    pk[0][0] = packbf(sv[0], sv[1]);
    pk[0][1] = packbf(sv[2], sv[3]);
    pk[1][0] = packbf(sv[4], sv[5]);
    pk[1][1] = packbf(sv[6], sv[7]);
    int base = ((quad & 1) * 2) * 16 + c;
    union { u32 u[4]; short8_t v; } pf;
    #pragma unroll
    for (int x = 0; x < 4; ++x) {
      int src = base + ((x >> 1) << 4);
      int v0 = __shfl((int)pk[0][x & 1], src);
      int v1 = __shfl((int)pk[1][x & 1], src);
      pf.u[x] = (quad < 2) ? (u32)v0 : (u32)v1;
    }
    // --- ctx^T += V^T_tile @ P^T : A-frag from VT rows (contiguous)
    const u16* vp = Vp + c * 2048 + kbase + quad * 8;
    O0 = __builtin_amdgcn_mfma_f32_16x16x32_bf16(*(const short8_t*)(vp),             pf.v, O0, 0, 0, 0);
    O1 = __builtin_amdgcn_mfma_f32_16x16x32_bf16(*(const short8_t*)(vp + 16 * 2048), pf.v, O1, 0, 0, 0);
    O2 = __builtin_amdgcn_mfma_f32_16x16x32_bf16(*(const short8_t*)(vp + 32 * 2048), pf.v, O2, 0, 0, 0);
    O3 = __builtin_amdgcn_mfma_f32_16x16x32_bf16(*(const short8_t*)(vp + 48 * 2048), pf.v, O3, 0, 0, 0);
  }
  float rl = 1.0f / l;
  // ctx[b][q][h*64 + d], d = dblk*16 + quad*4 + r  -> 4 bf16 packed per dblk
  u16* op = ctx + ((b * 2048 + q0 + c) * 1024 + h * 64 + quad * 4);
  float4_t Oa[4] = {O0, O1, O2, O3};
  #pragma unroll
  for (int dblk = 0; dblk < 4; ++dblk) {
    union { u32 u[2]; u64 ll; } ov;
    ov.u[0] = packbf(Oa[dblk][0] * rl, Oa[dblk][1] * rl);
    ov.u[1] = packbf(Oa[dblk][2] * rl, Oa[dblk][3] * rl);
    *(u64*)(op + dblk * 16) = ov.ll;
  }
}

// ---------- launch ----------
extern "C" void kernel_launch(void* const* d_in, const int* in_sizes, int n_in,
                              void* d_out, int out_size, void* d_ws, size_t ws_size,
                              hipStream_t stream) {
  const float* X    = (const float*)d_in[0];
  const float* mask = (const float*)d_in[1];
  const float* Wq   = (const float*)d_in[2];
  const float* bq   = (const float*)d_in[3];
  const float* Wk   = (const float*)d_in[4];
  const float* bk   = (const float*)d_in[5];
  const float* Wv   = (const float*)d_in[6];
  const float* bv   = (const float*)d_in[7];
  const float* Wo   = (const float*)d_in[8];
  const float* bo   = (const float*)d_in[9];

  char* w = (char*)d_ws;
  u16* Xb  = (u16*)(w);                    // 8 MB  [4096,1024] bf16
  u16* WqT = (u16*)(w + (8ull  << 20));    // 2 MB each, [N,K] bf16
  u16* WkT = (u16*)(w + (10ull << 20));
  u16* WvT = (u16*)(w + (12ull << 20));
  u16* WoT = (u16*)(w + (14ull << 20));
  u16* Qb  = (u16*)(w + (16ull << 20));    // 8 MB [B,H,S,64]
  u16* Kb  = (u16*)(w + (24ull << 20));    // 8 MB [B,H,S,64]
  u16* VTb = (u16*)(w + (32ull << 20));    // 8 MB [B,H,64,S]
  u16* Ctx = (u16*)(w + (40ull << 20));    // 8 MB [4096,1024]

  convert_x<<<4096, 256, 0, stream>>>(X, Xb);
  dim3 tb(32, 8), tg(32, 32);
  transpose_w<<<tg, tb, 0, stream>>>(Wq, WqT);
  transpose_w<<<tg, tb, 0, stream>>>(Wk, WkT);
  transpose_w<<<tg, tb, 0, stream>>>(Wv, WvT);
  transpose_w<<<tg, tb, 0, stream>>>(Wo, WoT);
  dim3 gg(32, 16);
  gemm_bf16<<<gg, 256, 0, stream>>>(Xb, WqT, bq, Qb, 0);
  gemm_bf16<<<gg, 256, 0, stream>>>(Xb, WkT, bk, Kb, 1);
  gemm_bf16<<<gg, 256, 0, stream>>>(Xb, WvT, bv, VTb, 2);
  attn_kernel<<<1024, 256, 0, stream>>>(Qb, Kb, VTb, mask, Ctx);
  gemm_bf16<<<gg, 256, 0, stream>>>(Ctx, WoT, bo, d_out, 3);
}

// Round 2
// 312.021 us; speedup vs baseline: 1.6738x; 1.6738x over previous
//
#include <hip/hip_runtime.h>

typedef __attribute__((ext_vector_type(8))) short short8_t;  // 8 bf16 (4 VGPRs)
typedef __attribute__((ext_vector_type(4))) float float4_t;  // MFMA C/D
typedef unsigned short u16;
typedef unsigned int u32;
typedef unsigned long long u64;

// ---------- helpers ----------
__device__ inline u16 f2bf(float x) {
  union { float f; u32 u; } v; v.f = x;
  u32 r = v.u + 0x7FFFu + ((v.u >> 16) & 1u);  // round-to-nearest-even
  return (u16)(r >> 16);
}
__device__ inline u32 packbf(float a, float b) {
  return (u32)f2bf(a) | ((u32)f2bf(b) << 16);
}
// async global->LDS DMA, 16B per lane; lds dest = wave-uniform base + lane*16
__device__ inline void async16(const u16* g, u16* l) {
  __builtin_amdgcn_global_load_lds(
      (const __attribute__((address_space(1))) unsigned int*)g,
      (__attribute__((address_space(3))) unsigned int*)l, 16, 0, 0);
}

// ---------- X fp32 -> bf16 ----------
__global__ __launch_bounds__(256) void convert_x(const float* __restrict__ X, u16* __restrict__ Xb) {
  int i = blockIdx.x * 256 + threadIdx.x;   // one float4 per thread
  float4_t x = ((const float4_t*)X)[i];
  union { u32 u[2]; u64 ll; } o;
  o.u[0] = packbf(x[0], x[1]);
  o.u[1] = packbf(x[2], x[3]);
  ((u64*)Xb)[i] = o.ll;
}

// ---------- W [K,N] fp32 -> WT [N,K] bf16 (1024x1024) ----------
__global__ __launch_bounds__(256) void transpose_w(const float* __restrict__ W, u16* __restrict__ WT) {
  __shared__ float t[32][33];
  int tx = threadIdx.x, ty = threadIdx.y;          // 32 x 8
  int r0 = blockIdx.y * 32, c0 = blockIdx.x * 32;  // r0: k, c0: n
  #pragma unroll
  for (int i = 0; i < 4; ++i)
    t[ty + i * 8][tx] = W[(r0 + ty + i * 8) * 1024 + c0 + tx];
  __syncthreads();
  #pragma unroll
  for (int i = 0; i < 4; ++i)
    WT[(c0 + ty + i * 8) * 1024 + r0 + tx] = f2bf(t[tx][ty + i * 8]);
}

// ---------- GEMM: C = A[4096,1024] * W (BT = W^T [1024,1024]) + bias ----------
// 128x64 C-tile per block (4 waves, each 64x32), BK=32, LDS-staged via global_load_lds.
// XOR chunk swizzle: LDS(row, lc) holds global chunk (lc ^ ((row>>1)&3)); applied at
// the global SOURCE address so the DMA dest stays linear (wave-uniform base + lane*16).
// mode 0: Q -> [B,H,S,64] bf16, scaled by 0.125
// mode 1: K -> [B,H,S,64] bf16
// mode 2: V -> [B,H,64,S] bf16 (transposed)
// mode 3: O -> [4096,1024] fp32 (d_out)
__global__ __launch_bounds__(256) void gemm_staged(const u16* __restrict__ A, const u16* __restrict__ BT,
                                                   const float* __restrict__ bias, void* __restrict__ outp,
                                                   int mode) {
  __shared__ __align__(16) u16 Als[128 * 32];  // 8 KB
  __shared__ __align__(16) u16 Bls[64 * 32];   // 4 KB
  int m0 = blockIdx.x * 128, n0 = blockIdx.y * 64;
  int lane = threadIdx.x & 63, wave = threadIdx.x >> 6;
  int quad = lane >> 4, c = lane & 15;
  int wm = wave >> 1, wn = wave & 1;

  // staging lane geometry: 4 lanes per 32-col row (16B chunks)
  int srow_off = lane >> 2;        // 0..15 within a 16-row group
  int lchunk = lane & 3;           // LDS chunk this lane fills
  int arow0 = wave * 16 + srow_off;        // A round 0 rows 0..63
  int arow1 = 64 + wave * 16 + srow_off;   // A round 1 rows 64..127
  int brow = wave * 16 + srow_off;         // B rows 0..63
  const u16* gA0 = A  + (size_t)(m0 + arow0) * 1024 + ((lchunk ^ ((arow0 >> 1) & 3)) << 3);
  const u16* gA1 = A  + (size_t)(m0 + arow1) * 1024 + ((lchunk ^ ((arow1 >> 1) & 3)) << 3);
  const u16* gB  = BT + (size_t)(n0 + brow) * 1024 + ((lchunk ^ ((brow  >> 1) & 3)) << 3);
  u16* lA0 = &Als[(wave * 16) * 32 + lane * 8];
  u16* lA1 = &Als[(64 + wave * 16) * 32 + lane * 8];
  u16* lB  = &Bls[(wave * 16) * 32 + lane * 8];

  // fragment read offsets (apply same swizzle)
  int ar[4], br[2];
  #pragma unroll
  for (int i = 0; i < 4; ++i) {
    int row = wm * 64 + i * 16 + c;
    ar[i] = row * 32 + ((quad ^ ((row >> 1) & 3)) << 3);
  }
  #pragma unroll
  for (int j = 0; j < 2; ++j) {
    int row = wn * 32 + j * 16 + c;
    br[j] = row * 32 + ((quad ^ ((row >> 1) & 3)) << 3);
  }

  float4_t acc[4][2] = {};
  for (int k0 = 0; k0 < 1024; k0 += 32) {
    async16(gA0 + k0, lA0);
    async16(gA1 + k0, lA1);
    async16(gB + k0, lB);
    __syncthreads();
    short8_t af[4], bfr[2];
    #pragma unroll
    for (int i = 0; i < 4; ++i) af[i] = *(const short8_t*)&Als[ar[i]];
    #pragma unroll
    for (int j = 0; j < 2; ++j) bfr[j] = *(const short8_t*)&Bls[br[j]];
    #pragma unroll
    for (int i = 0; i < 4; ++i)
      #pragma unroll
      for (int j = 0; j < 2; ++j)
        acc[i][j] = __builtin_amdgcn_mfma_f32_16x16x32_bf16(af[i], bfr[j], acc[i][j], 0, 0, 0);
    __syncthreads();
  }

  int mrow = m0 + wm * 64, ncol = n0 + wn * 32;
  #pragma unroll
  for (int i = 0; i < 4; ++i) {
    #pragma unroll
    for (int j = 0; j < 2; ++j) {
      int colb = ncol + j * 16 + c;
      float bv = bias[colb];
      int rowb = mrow + i * 16 + quad * 4;  // rows rowb..rowb+3
      if (mode == 2) {
        int b = rowb >> 11, s = rowb & 2047;
        int h = colb >> 6, d = colb & 63;
        u16* o = (u16*)outp + (((b * 16 + h) * 64 + d) * 2048 + s);
        union { u32 u[2]; u64 ll; } ov;
        ov.u[0] = packbf(acc[i][j][0] + bv, acc[i][j][1] + bv);
        ov.u[1] = packbf(acc[i][j][2] + bv, acc[i][j][3] + bv);
        *(u64*)o = ov.ll;
      } else if (mode == 3) {
        float* o = (float*)outp;
        #pragma unroll
        for (int r = 0; r < 4; ++r)
          o[(rowb + r) * 1024 + colb] = acc[i][j][r] + bv;
      } else {
        float sc = (mode == 0) ? 0.125f : 1.0f;
        u16* o = (u16*)outp;
        #pragma unroll
        for (int r = 0; r < 4; ++r) {
          int row = rowb + r;
          int b = row >> 11, s = row & 2047;
          int h = colb >> 6, d = colb & 63;
          o[(((b * 16 + h) * 2048 + s) << 6) + d] = f2bf((acc[i][j][r] + bv) * sc);
        }
      }
    }
  }
}

// ---------- flash attention: S^T = K Q^T, online softmax, ctx^T = V^T P^T ----------
// Q,K: [B,H,S,64] bf16 (Q pre-scaled by 1/8); VT: [B,H,64,S] bf16
// ctx out: [B,S,1024] bf16
// Balance: block j (within each b,h) runs q-tiles {j, 63-j, 64+j, 127-j} -> per-block
// causal trip-sum is constant (~131 k-tiles), so all 1024 blocks do equal work.
__global__ __launch_bounds__(256) void attn_kernel(const u16* __restrict__ Q, const u16* __restrict__ K,
                                                   const u16* __restrict__ VT, const float* __restrict__ mask,
                                                   u16* __restrict__ ctx) {
  const float LOG2E = 1.4426950408889634f;
  int wavei = threadIdx.x >> 6;
  int lane = threadIdx.x & 63;
  int quad = lane >> 4, c = lane & 15;
  int bh = blockIdx.x >> 5;   // 0..31
  int j = blockIdx.x & 31;    // 0..31
  int qtab[4] = {j, 63 - j, 64 + j, 127 - j};
  int qblk = qtab[wavei];
  int b = bh >> 4, h = bh & 15;
  int q0 = qblk << 4;
  const u16* Qp = Q + (((bh) * 2048 + q0) << 6);
  const u16* Kp = K + ((size_t)bh << 17);
  const u16* Vp = VT + ((size_t)bh << 17);
  const float* mp = mask + (b << 11);

  // Q^T B-operand fragments: lane holds Q[q0+c][quad*8+j (+32)]
  short8_t qf0 = *(const short8_t*)(Qp + c * 64 + quad * 8);
  short8_t qf1 = *(const short8_t*)(Qp + c * 64 + 32 + quad * 8);

  float4_t O0 = {}, O1 = {}, O2 = {}, O3 = {};  // ctx^T, d-blocks of 16
  float m = -1e30f, l = 0.0f;
  int qg = q0 + c;
  int tmax = (q0 + 15) >> 5;
  for (int t = 0; t <= tmax; ++t) {
    int kbase = t << 5;
    // --- issue all loads up front: K frags, V frags, mask vectors
    const u16* kp = Kp + (kbase + c) * 64 + quad * 8;
    short8_t ka0 = *(const short8_t*)(kp);
    short8_t ka1 = *(const short8_t*)(kp + 32);
    short8_t kb0 = *(const short8_t*)(kp + 16 * 64);
    short8_t kb1 = *(const short8_t*)(kp + 16 * 64 + 32);
    const u16* vp = Vp + c * 2048 + kbase + quad * 8;
    short8_t vf0 = *(const short8_t*)(vp);
    short8_t vf1 = *(const short8_t*)(vp + 16 * 2048);
    short8_t vf2 = *(const short8_t*)(vp + 32 * 2048);
    short8_t vf3 = *(const short8_t*)(vp + 48 * 2048);
    float4_t mv0 = *(const float4_t*)(mp + kbase + quad * 4);
    float4_t mv1 = *(const float4_t*)(mp + kbase + 16 + quad * 4);
    // --- S^T = K_tile @ Q^T : D[kpos][q], kpos = quad*4+r (+16*blk), q = c
    float4_t s0 = {}, s1 = {};
    s0 = __builtin_amdgcn_mfma_f32_16x16x32_bf16(ka0, qf0, s0, 0, 0, 0);
    s0 = __builtin_amdgcn_mfma_f32_16x16x32_bf16(ka1, qf1, s0, 0, 0, 0);
    s1 = __builtin_amdgcn_mfma_f32_16x16x32_bf16(kb0, qf0, s1, 0, 0, 0);
    s1 = __builtin_amdgcn_mfma_f32_16x16x32_bf16(kb1, qf1, s1, 0, 0, 0);
    float sv[8];
    #pragma unroll
    for (int r = 0; r < 4; ++r) { sv[r] = s0[r]; sv[4 + r] = s1[r]; }
    // --- masks + online softmax (per-lane state: column q = q0+c)
    float smax = -1e30f;
    #pragma unroll
    for (int e = 0; e < 8; ++e) {
      int kpos = kbase + ((e >> 2) << 4) + quad * 4 + (e & 3);
      float mval = (e < 4) ? mv0[e & 3] : mv1[e & 3];
      float sc = sv[e];
      sc += (1.0f - mval) * -10000.0f;         // padding mask
      sc += (kpos > qg) ? -1e10f : 0.0f;       // causal mask
      sv[e] = sc;
      smax = fmaxf(smax, sc);
    }
    smax = fmaxf(smax, __shfl_xor(smax, 16));
    smax = fmaxf(smax, __shfl_xor(smax, 32));
    float mn = fmaxf(m, smax);
    float alpha = exp2f((m - mn) * LOG2E);
    float psum = 0.0f;
    #pragma unroll
    for (int e = 0; e < 8; ++e) {
      float p = exp2f((sv[e] - mn) * LOG2E);
      sv[e] = p;
      psum += p;
    }
    psum += __shfl_xor(psum, 16);
    psum += __shfl_xor(psum, 32);
    l = l * alpha + psum;
    m = mn;
    O0 *= alpha; O1 *= alpha; O2 *= alpha; O3 *= alpha;
    // --- P^T (C-layout) -> B-operand layout via packed-bf16 shuffles
    u32 pk[2][2];
    pk[0][0] = packbf(sv[0], sv[1]);
    pk[0][1] = packbf(sv[2], sv[3]);
    pk[1][0] = packbf(sv[4], sv[5]);
    pk[1][1] = packbf(sv[6], sv[7]);
    int base = ((quad & 1) * 2) * 16 + c;
    union { u32 u[4]; short8_t v; } pf;
    #pragma unroll
    for (int x = 0; x < 4; ++x) {
      int src = base + ((x >> 1) << 4);
      int v0 = __shfl((int)pk[0][x & 1], src);
      int v1 = __shfl((int)pk[1][x & 1], src);
      pf.u[x] = (quad < 2) ? (u32)v0 : (u32)v1;
    }
    // --- ctx^T += V^T_tile @ P^T : A-frag from VT rows (contiguous)
    O0 = __builtin_amdgcn_mfma_f32_16x16x32_bf16(vf0, pf.v, O0, 0, 0, 0);
    O1 = __builtin_amdgcn_mfma_f32_16x16x32_bf16(vf1, pf.v, O1, 0, 0, 0);
    O2 = __builtin_amdgcn_mfma_f32_16x16x32_bf16(vf2, pf.v, O2, 0, 0, 0);
    O3 = __builtin_amdgcn_mfma_f32_16x16x32_bf16(vf3, pf.v, O3, 0, 0, 0);
  }
  float rl = 1.0f / l;
  // ctx[b][q][h*64 + d], d = dblk*16 + quad*4 + r  -> 4 bf16 packed per dblk
  u16* op = ctx + ((b * 2048 + q0 + c) * 1024 + h * 64 + quad * 4);
  float4_t Oa[4] = {O0, O1, O2, O3};
  #pragma unroll
  for (int dblk = 0; dblk < 4; ++dblk) {
    union { u32 u[2]; u64 ll; } ov;
    ov.u[0] = packbf(Oa[dblk][0] * rl, Oa[dblk][1] * rl);
    ov.u[1] = packbf(Oa[dblk][2] * rl, Oa[dblk][3] * rl);
    *(u64*)(op + dblk * 16) = ov.ll;
  }
}

// ---------- launch ----------
extern "C" void kernel_launch(void* const* d_in, const int* in_sizes, int n_in,
                              void* d_out, int out_size, void* d_ws, size_t ws_size,
                              hipStream_t stream) {
  const float* X    = (const float*)d_in[0];
  const float* mask = (const float*)d_in[1];
  const float* Wq   = (const float*)d_in[2];
  const float* bq   = (const float*)d_in[3];
  const float* Wk   = (const float*)d_in[4];
  const float* bk   = (const float*)d_in[5];
  const float* Wv   = (const float*)d_in[6];
  const float* bv   = (const float*)d_in[7];
  const float* Wo   = (const float*)d_in[8];
  const float* bo   = (const float*)d_in[9];

  char* w = (char*)d_ws;
  u16* Xb  = (u16*)(w);                    // 8 MB  [4096,1024] bf16
  u16* WqT = (u16*)(w + (8ull  << 20));    // 2 MB each, [N,K] bf16
  u16* WkT = (u16*)(w + (10ull << 20));
  u16* WvT = (u16*)(w + (12ull << 20));
  u16* WoT = (u16*)(w + (14ull << 20));
  u16* Qb  = (u16*)(w + (16ull << 20));    // 8 MB [B,H,S,64]
  u16* Kb  = (u16*)(w + (24ull << 20));    // 8 MB [B,H,S,64]
  u16* VTb = (u16*)(w + (32ull << 20));    // 8 MB [B,H,64,S]
  u16* Ctx = (u16*)(w + (40ull << 20));    // 8 MB [4096,1024]

  convert_x<<<4096, 256, 0, stream>>>(X, Xb);
  dim3 tb(32, 8), tg(32, 32);
  transpose_w<<<tg, tb, 0, stream>>>(Wq, WqT);
  transpose_w<<<tg, tb, 0, stream>>>(Wk, WkT);
  transpose_w<<<tg, tb, 0, stream>>>(Wv, WvT);
  transpose_w<<<tg, tb, 0, stream>>>(Wo, WoT);
  dim3 gg(32, 16);
  gemm_staged<<<gg, 256, 0, stream>>>(Xb, WqT, bq, Qb, 0);
  gemm_staged<<<gg, 256, 0, stream>>>(Xb, WkT, bk, Kb, 1);
  gemm_staged<<<gg, 256, 0, stream>>>(Xb, WvT, bv, VTb, 2);
  attn_kernel<<<1024, 256, 0, stream>>>(Qb, Kb, VTb, mask, Ctx);
  gemm_staged<<<gg, 256, 0, stream>>>(Ctx, WoT, bo, d_out, 3);
}

// Round 3
// 254.231 us; speedup vs baseline: 2.0542x; 1.2273x over previous
//
#include <hip/hip_runtime.h>

typedef __attribute__((ext_vector_type(8))) short short8_t;  // 8 bf16 (4 VGPRs)
typedef __attribute__((ext_vector_type(4))) float float4_t;  // MFMA C/D
typedef unsigned short u16;
typedef unsigned int u32;
typedef unsigned long long u64;

// ---------- helpers ----------
__device__ inline u16 f2bf(float x) {
  union { float f; u32 u; } v; v.f = x;
  u32 r = v.u + 0x7FFFu + ((v.u >> 16) & 1u);  // round-to-nearest-even
  return (u16)(r >> 16);
}
__device__ inline u32 packbf(float a, float b) {
  return (u32)f2bf(a) | ((u32)f2bf(b) << 16);
}
// async global->LDS DMA, 16B per lane; lds dest = wave-uniform base + lane*16
__device__ inline void async16(const u16* g, u16* l) {
  __builtin_amdgcn_global_load_lds(
      (const __attribute__((address_space(1))) unsigned int*)g,
      (__attribute__((address_space(3))) unsigned int*)l, 16, 0, 0);
}

// ---------- X fp32 -> bf16 ----------
__global__ __launch_bounds__(256) void convert_x(const float* __restrict__ X, u16* __restrict__ Xb) {
  int i = blockIdx.x * 256 + threadIdx.x;   // one float4 per thread
  float4_t x = ((const float4_t*)X)[i];
  union { u32 u[2]; u64 ll; } o;
  o.u[0] = packbf(x[0], x[1]);
  o.u[1] = packbf(x[2], x[3]);
  ((u64*)Xb)[i] = o.ll;
}

// ---------- W [K,N] fp32 -> WT [N,K] bf16 (1024x1024) ----------
__global__ __launch_bounds__(256) void transpose_w(const float* __restrict__ W, u16* __restrict__ WT) {
  __shared__ float t[32][33];
  int tx = threadIdx.x, ty = threadIdx.y;          // 32 x 8
  int r0 = blockIdx.y * 32, c0 = blockIdx.x * 32;  // r0: k, c0: n
  #pragma unroll
  for (int i = 0; i < 4; ++i)
    t[ty + i * 8][tx] = W[(r0 + ty + i * 8) * 1024 + c0 + tx];
  __syncthreads();
  #pragma unroll
  for (int i = 0; i < 4; ++i)
    WT[(c0 + ty + i * 8) * 1024 + r0 + tx] = f2bf(t[tx][ty + i * 8]);
}

// ---------- GEMM: 128x128 C-tile, 4 waves each 64x64, BK=32, LDS via global_load_lds ----------
// XOR chunk swizzle on global source address (DMA dest stays linear); 2-way LDS conflict = free.
// mode 4 (fused QKV): A=[4096,1024], BT=[3072,1024]; col block 0->Q(x0.125) o0 [B,H,S,64],
//   1->K o1 [B,H,S,64], 2->V o2 [B,H,64,S] (transposed). biases selected by colb>>10.
// mode 3: O-proj, fp32 out o0 [4096,1024] + bias0.
__global__ __launch_bounds__(256) void gemm128(const u16* __restrict__ A, const u16* __restrict__ BT,
                                               const float* __restrict__ bias0, const float* __restrict__ bias1,
                                               const float* __restrict__ bias2,
                                               void* __restrict__ o0, void* __restrict__ o1, void* __restrict__ o2,
                                               int mode) {
  __shared__ __align__(16) u16 Als[128 * 32];  // 8 KB
  __shared__ __align__(16) u16 Bls[128 * 32];  // 8 KB
  const int m0 = blockIdx.x * 128, n0 = blockIdx.y * 128;
  const int lane = threadIdx.x & 63, wave = threadIdx.x >> 6;
  const int quad = lane >> 4, c = lane & 15;
  const int wm = wave >> 1, wn = wave & 1;

  const int srow = lane >> 2, lchunk = lane & 3;
  const int r0 = wave * 16 + srow, r1 = 64 + wave * 16 + srow;
  const u16* gA0 = A  + (size_t)(m0 + r0) * 1024 + ((lchunk ^ ((r0 >> 1) & 3)) << 3);
  const u16* gA1 = A  + (size_t)(m0 + r1) * 1024 + ((lchunk ^ ((r1 >> 1) & 3)) << 3);
  const u16* gB0 = BT + (size_t)(n0 + r0) * 1024 + ((lchunk ^ ((r0 >> 1) & 3)) << 3);
  const u16* gB1 = BT + (size_t)(n0 + r1) * 1024 + ((lchunk ^ ((r1 >> 1) & 3)) << 3);
  u16* lA0 = &Als[(wave * 16) * 32 + lane * 8];
  u16* lA1 = &Als[(64 + wave * 16) * 32 + lane * 8];
  u16* lB0 = &Bls[(wave * 16) * 32 + lane * 8];
  u16* lB1 = &Bls[(64 + wave * 16) * 32 + lane * 8];

  int ar[4], br[4];
  #pragma unroll
  for (int i = 0; i < 4; ++i) {
    int row = wm * 64 + i * 16 + c;
    ar[i] = row * 32 + ((quad ^ ((row >> 1) & 3)) << 3);
  }
  #pragma unroll
  for (int j = 0; j < 4; ++j) {
    int row = wn * 64 + j * 16 + c;
    br[j] = row * 32 + ((quad ^ ((row >> 1) & 3)) << 3);
  }

  float4_t acc[4][4] = {};
  for (int k0 = 0; k0 < 1024; k0 += 32) {
    async16(gA0 + k0, lA0);
    async16(gA1 + k0, lA1);
    async16(gB0 + k0, lB0);
    async16(gB1 + k0, lB1);
    __syncthreads();
    short8_t af[4], bfr[4];
    #pragma unroll
    for (int i = 0; i < 4; ++i) af[i] = *(const short8_t*)&Als[ar[i]];
    #pragma unroll
    for (int j = 0; j < 4; ++j) bfr[j] = *(const short8_t*)&Bls[br[j]];
    #pragma unroll
    for (int i = 0; i < 4; ++i)
      #pragma unroll
      for (int j = 0; j < 4; ++j)
        acc[i][j] = __builtin_amdgcn_mfma_f32_16x16x32_bf16(af[i], bfr[j], acc[i][j], 0, 0, 0);
    __syncthreads();
  }

  const int mrow = m0 + wm * 64, ncol = n0 + wn * 64;
  if (mode == 3) {
    float* o = (float*)o0;
    #pragma unroll
    for (int i = 0; i < 4; ++i) {
      #pragma unroll
      for (int j = 0; j < 4; ++j) {
        int colb = ncol + j * 16 + c;
        float bv = bias0[colb];
        int rowb = mrow + i * 16 + quad * 4;
        #pragma unroll
        for (int r = 0; r < 4; ++r)
          o[(size_t)(rowb + r) * 1024 + colb] = acc[i][j][r] + bv;
      }
    }
  } else {
    #pragma unroll
    for (int j = 0; j < 4; ++j) {
      int colb = ncol + j * 16 + c;     // 0..3071
      int which = colb >> 10;           // 0:Q 1:K 2:V (uniform per j)
      int n1 = colb & 1023, h = n1 >> 6, d = n1 & 63;
      const float* bp = (which == 0) ? bias0 : (which == 1 ? bias1 : bias2);
      float bv = bp[n1];
      #pragma unroll
      for (int i = 0; i < 4; ++i) {
        int rowb = mrow + i * 16 + quad * 4;
        int b = rowb >> 11, s = rowb & 2047;
        if (which == 2) {
          u16* o = (u16*)o2 + (((size_t)(b * 16 + h) * 64 + d) * 2048 + s);
          union { u32 u[2]; u64 ll; } ov;
          ov.u[0] = packbf(acc[i][j][0] + bv, acc[i][j][1] + bv);
          ov.u[1] = packbf(acc[i][j][2] + bv, acc[i][j][3] + bv);
          *(u64*)o = ov.ll;
        } else {
          float sc = (which == 0) ? 0.125f : 1.0f;
          u16* o = (u16*)((which == 0) ? o0 : o1);
          #pragma unroll
          for (int r = 0; r < 4; ++r)
            o[(((size_t)(b * 16 + h) * 2048 + (s + r)) << 6) + d] = f2bf((acc[i][j][r] + bv) * sc);
        }
      }
    }
  }
}

// ---------- softmax half: S^T fragment -> P^T B-operand fragment (fixed-base exp) ----------
__device__ inline short8_t half_softmax(float4_t s0, float4_t s1, float4_t mpl0, float4_t mpl1,
                                        bool diag, int kbase, int quad, int c, int qg, float& lacc) {
  const float LOG2E = 1.4426950408889634f;
  float p[8];
  #pragma unroll
  for (int e = 0; e < 8; ++e) {
    float sv = (e < 4) ? s0[e] : s1[e - 4];
    float ml = (e < 4) ? mpl0[e] : mpl1[e - 4];
    float arg = __builtin_fmaf(sv, LOG2E, ml);
    if (diag) {
      int kpos = kbase + ((e >> 2) << 4) + quad * 4 + (e & 3);
      arg = (kpos > qg) ? -50.0f : arg;   // exp2(-50) ~ 9e-16 ~ 0
    }
    float pe = exp2f(arg);
    p[e] = pe;
    lacc += pe;
  }
  u32 pk0[2] = {packbf(p[0], p[1]), packbf(p[2], p[3])};
  u32 pk1[2] = {packbf(p[4], p[5]), packbf(p[6], p[7])};
  int base = ((quad & 1) * 2) * 16 + c;
  union { u32 u[4]; short8_t v; } pf;
  #pragma unroll
  for (int x = 0; x < 4; ++x) {
    int src = base + ((x >> 1) << 4);
    int v0 = __shfl((int)pk0[x & 1], src);
    int v1 = __shfl((int)pk1[x & 1], src);
    pf.u[x] = (quad < 2) ? (u32)v0 : (u32)v1;
  }
  return pf.v;
}

// ---------- flash attention, 4-way K-split, fixed-base softmax ----------
// Q,K: [B,H,S,64] bf16 (Q pre-scaled 1/8); VT: [B,H,64,S]; ctx: [B,S,1024] bf16.
// Block = 4 waves on one 32-query unit; waves take K-tiles strided by 4 (additively
// combinable since no running max); partial O (2x4 float4) + l combined through LDS.
// Two phases per block: units u and 63-u -> balanced ~17 K-tiles per wave per block.
__global__ __launch_bounds__(256) void attn_kernel(const u16* __restrict__ Q, const u16* __restrict__ K,
                                                   const u16* __restrict__ VT, const float* __restrict__ mask,
                                                   u16* __restrict__ ctx) {
  __shared__ float cmb[4][64][36];  // [wave][lane][16 OA + 16 OB + lA + lB + pad]
  const float C1 = 10000.0f * 1.4426950408889634f;
  int w = threadIdx.x >> 6, lane = threadIdx.x & 63;
  int quad = lane >> 4, c = lane & 15;
  int bh = blockIdx.x >> 5, pr = blockIdx.x & 31;
  int b = bh >> 4, h = bh & 15;
  const u16* Kp = K + ((size_t)bh << 17);
  const u16* Vp = VT + ((size_t)bh << 17);
  const float* mp = mask + (b << 11);

  #pragma unroll 1
  for (int ph = 0; ph < 2; ++ph) {
    int u = ph ? (63 - pr) : pr;  // 32-query unit, q in [32u, 32u+32)
    int q0 = u << 5;
    const u16* Qp = Q + (((size_t)bh * 2048 + q0 + c) << 6) + quad * 8;
    short8_t qA0 = *(const short8_t*)(Qp);
    short8_t qA1 = *(const short8_t*)(Qp + 32);
    short8_t qB0 = *(const short8_t*)(Qp + 1024);
    short8_t qB1 = *(const short8_t*)(Qp + 1024 + 32);
    float4_t OA[4] = {}, OB[4] = {};
    float lA = 0.0f, lB = 0.0f;
    int qgA = q0 + c, qgB = q0 + 16 + c;
    for (int t = w; t <= u; t += 4) {
      int kbase = t << 5;
      const u16* kp = Kp + (((size_t)kbase + c) << 6) + quad * 8;
      short8_t ka0 = *(const short8_t*)(kp);
      short8_t ka1 = *(const short8_t*)(kp + 32);
      short8_t kb0 = *(const short8_t*)(kp + 1024);
      short8_t kb1 = *(const short8_t*)(kp + 1024 + 32);
      const u16* vp = Vp + (size_t)c * 2048 + kbase + quad * 8;
      short8_t vf0 = *(const short8_t*)(vp);
      short8_t vf1 = *(const short8_t*)(vp + 16 * 2048);
      short8_t vf2 = *(const short8_t*)(vp + 32 * 2048);
      short8_t vf3 = *(const short8_t*)(vp + 48 * 2048);
      float4_t mv0 = *(const float4_t*)(mp + kbase + quad * 4);
      float4_t mv1 = *(const float4_t*)(mp + kbase + 16 + quad * 4);
      float4_t mpl0 = (mv0 - 1.0f) * C1;  // (1-m)*-10000*log2e
      float4_t mpl1 = (mv1 - 1.0f) * C1;
      bool diag = (t == u);
      float4_t sA0 = {}, sA1 = {}, sB0 = {}, sB1 = {};
      sA0 = __builtin_amdgcn_mfma_f32_16x16x32_bf16(ka0, qA0, sA0, 0, 0, 0);
      sA0 = __builtin_amdgcn_mfma_f32_16x16x32_bf16(ka1, qA1, sA0, 0, 0, 0);
      sA1 = __builtin_amdgcn_mfma_f32_16x16x32_bf16(kb0, qA0, sA1, 0, 0, 0);
      sA1 = __builtin_amdgcn_mfma_f32_16x16x32_bf16(kb1, qA1, sA1, 0, 0, 0);
      sB0 = __builtin_amdgcn_mfma_f32_16x16x32_bf16(ka0, qB0, sB0, 0, 0, 0);
      sB0 = __builtin_amdgcn_mfma_f32_16x16x32_bf16(ka1, qB1, sB0, 0, 0, 0);
      sB1 = __builtin_amdgcn_mfma_f32_16x16x32_bf16(kb0, qB0, sB1, 0, 0, 0);
      sB1 = __builtin_amdgcn_mfma_f32_16x16x32_bf16(kb1, qB1, sB1, 0, 0, 0);
      short8_t pfA = half_softmax(sA0, sA1, mpl0, mpl1, diag, kbase, quad, c, qgA, lA);
      short8_t pfB = half_softmax(sB0, sB1, mpl0, mpl1, diag, kbase, quad, c, qgB, lB);
      OA[0] = __builtin_amdgcn_mfma_f32_16x16x32_bf16(vf0, pfA, OA[0], 0, 0, 0);
      OA[1] = __builtin_amdgcn_mfma_f32_16x16x32_bf16(vf1, pfA, OA[1], 0, 0, 0);
      OA[2] = __builtin_amdgcn_mfma_f32_16x16x32_bf16(vf2, pfA, OA[2], 0, 0, 0);
      OA[3] = __builtin_amdgcn_mfma_f32_16x16x32_bf16(vf3, pfA, OA[3], 0, 0, 0);
      OB[0] = __builtin_amdgcn_mfma_f32_16x16x32_bf16(vf0, pfB, OB[0], 0, 0, 0);
      OB[1] = __builtin_amdgcn_mfma_f32_16x16x32_bf16(vf1, pfB, OB[1], 0, 0, 0);
      OB[2] = __builtin_amdgcn_mfma_f32_16x16x32_bf16(vf2, pfB, OB[2], 0, 0, 0);
      OB[3] = __builtin_amdgcn_mfma_f32_16x16x32_bf16(vf3, pfB, OB[3], 0, 0, 0);
    }
    // write partials
    float* cw = &cmb[w][lane][0];
    *(float4_t*)(cw + 0)  = OA[0];
    *(float4_t*)(cw + 4)  = OA[1];
    *(float4_t*)(cw + 8)  = OA[2];
    *(float4_t*)(cw + 12) = OA[3];
    *(float4_t*)(cw + 16) = OB[0];
    *(float4_t*)(cw + 20) = OB[1];
    *(float4_t*)(cw + 24) = OB[2];
    *(float4_t*)(cw + 28) = OB[3];
    cw[32] = lA;
    cw[33] = lB;
    __syncthreads();
    // wave w reduces dblk w for both halves
    float4_t sA = {}, sB = {};
    float la = 0.0f, lb = 0.0f;
    #pragma unroll
    for (int w2 = 0; w2 < 4; ++w2) {
      const float* cr = &cmb[w2][lane][0];
      sA += *(const float4_t*)(cr + w * 4);
      sB += *(const float4_t*)(cr + 16 + w * 4);
      float4_t l4 = *(const float4_t*)(cr + 32);
      la += l4[0];
      lb += l4[1];
    }
    la += __shfl_xor(la, 16); la += __shfl_xor(la, 32);
    lb += __shfl_xor(lb, 16); lb += __shfl_xor(lb, 32);
    float rA = 1.0f / la, rB = 1.0f / lb;
    u16* opA = ctx + ((size_t)(b * 2048 + q0 + c) * 1024 + h * 64 + w * 16 + quad * 4);
    u16* opB = opA + (size_t)16 * 1024;
    union { u32 uu[2]; u64 ll; } ov;
    ov.uu[0] = packbf(sA[0] * rA, sA[1] * rA);
    ov.uu[1] = packbf(sA[2] * rA, sA[3] * rA);
    *(u64*)opA = ov.ll;
    ov.uu[0] = packbf(sB[0] * rB, sB[1] * rB);
    ov.uu[1] = packbf(sB[2] * rB, sB[3] * rB);
    *(u64*)opB = ov.ll;
    __syncthreads();  // protect LDS reuse by next phase
  }
}

// ---------- launch ----------
extern "C" void kernel_launch(void* const* d_in, const int* in_sizes, int n_in,
                              void* d_out, int out_size, void* d_ws, size_t ws_size,
                              hipStream_t stream) {
  const float* X    = (const float*)d_in[0];
  const float* mask = (const float*)d_in[1];
  const float* Wq   = (const float*)d_in[2];
  const float* bq   = (const float*)d_in[3];
  const float* Wk   = (const float*)d_in[4];
  const float* bk   = (const float*)d_in[5];
  const float* Wv   = (const float*)d_in[6];
  const float* bv   = (const float*)d_in[7];
  const float* Wo   = (const float*)d_in[8];
  const float* bo   = (const float*)d_in[9];

  char* w = (char*)d_ws;
  u16* Xb     = (u16*)(w);                 // 8 MB  [4096,1024] bf16
  u16* WqkvT  = (u16*)(w + (8ull  << 20)); // 6 MB  [3072,1024] bf16 (Q|K|V transposed)
  u16* WoT    = (u16*)(w + (14ull << 20)); // 2 MB  [1024,1024] bf16
  u16* Qb     = (u16*)(w + (16ull << 20)); // 8 MB [B,H,S,64]
  u16* Kb     = (u16*)(w + (24ull << 20)); // 8 MB [B,H,S,64]
  u16* VTb    = (u16*)(w + (32ull << 20)); // 8 MB [B,H,64,S]
  u16* Ctx    = (u16*)(w + (40ull << 20)); // 8 MB [4096,1024]

  convert_x<<<4096, 256, 0, stream>>>(X, Xb);
  dim3 tb(32, 8), tg(32, 32);
  transpose_w<<<tg, tb, 0, stream>>>(Wq, WqkvT);
  transpose_w<<<tg, tb, 0, stream>>>(Wk, WqkvT + 1024 * 1024);
  transpose_w<<<tg, tb, 0, stream>>>(Wv, WqkvT + 2048 * 1024);
  transpose_w<<<tg, tb, 0, stream>>>(Wo, WoT);
  gemm128<<<dim3(32, 24), 256, 0, stream>>>(Xb, WqkvT, bq, bk, bv, Qb, Kb, VTb, 4);
  attn_kernel<<<1024, 256, 0, stream>>>(Qb, Kb, VTb, mask, Ctx);
  gemm128<<<dim3(32, 8), 256, 0, stream>>>(Ctx, WoT, bo, bo, bo, d_out, d_out, d_out, 3);
}

// Round 4
// 233.088 us; speedup vs baseline: 2.2406x; 1.0907x over previous
//
#include <hip/hip_runtime.h>

typedef __attribute__((ext_vector_type(8))) short short8_t;  // 8 bf16 (4 VGPRs)
typedef __attribute__((ext_vector_type(4))) float float4_t;  // MFMA C/D
typedef unsigned short u16;
typedef unsigned int u32;
typedef unsigned long long u64;

// ---------- helpers ----------
__device__ inline u16 f2bf(float x) {
  union { float f; u32 u; } v; v.f = x;
  u32 r = v.u + 0x7FFFu + ((v.u >> 16) & 1u);  // round-to-nearest-even
  return (u16)(r >> 16);
}
__device__ inline u32 packbf(float a, float b) {
  return (u32)f2bf(a) | ((u32)f2bf(b) << 16);
}
// async global->LDS DMA, 16B per lane; lds dest = wave-uniform base + lane*16
__device__ inline void async16(const u16* g, u16* l) {
  __builtin_amdgcn_global_load_lds(
      (const __attribute__((address_space(1))) unsigned int*)g,
      (__attribute__((address_space(3))) unsigned int*)l, 16, 0, 0);
}

// ---------- fused prologue: X fp32->bf16 (blocks 0..4095), W transposes (4096..8191) ----------
__global__ __launch_bounds__(256) void prologue(const float* __restrict__ X,
                                                const float* __restrict__ Wq, const float* __restrict__ Wk,
                                                const float* __restrict__ Wv, const float* __restrict__ Wo,
                                                u16* __restrict__ Xb, u16* __restrict__ WqkvT,
                                                u16* __restrict__ WoT) {
  __shared__ float tls[32][33];
  int bid = blockIdx.x;
  if (bid < 4096) {
    int i = bid * 256 + threadIdx.x;  // one float4 per thread
    float4_t x = ((const float4_t*)X)[i];
    union { u32 u[2]; u64 ll; } o;
    o.u[0] = packbf(x[0], x[1]);
    o.u[1] = packbf(x[2], x[3]);
    ((u64*)Xb)[i] = o.ll;
  } else {
    int t = bid - 4096;
    int mat = t >> 10, tile = t & 1023;
    const float* W = (mat == 0) ? Wq : (mat == 1) ? Wk : (mat == 2) ? Wv : Wo;
    u16* WT = (mat < 3) ? WqkvT + ((size_t)mat << 20) : WoT;
    int tx = threadIdx.x & 31, ty = threadIdx.x >> 5;  // 32 x 8
    int c0 = (tile & 31) * 32, r0 = (tile >> 5) * 32;  // r0: k, c0: n
    #pragma unroll
    for (int i = 0; i < 4; ++i)
      tls[ty + i * 8][tx] = W[(r0 + ty + i * 8) * 1024 + c0 + tx];
    __syncthreads();
    #pragma unroll
    for (int i = 0; i < 4; ++i)
      WT[(size_t)(c0 + ty + i * 8) * 1024 + r0 + tx] = f2bf(tls[tx][ty + i * 8]);
  }
}

// ---------- GEMM: 128x128 C-tile, 4 waves each 64x64, BK=64 (32 MFMA per barrier-pair) ----------
// LDS staged via global_load_lds; XOR chunk swizzle (8 chunks/row) applied at the global
// SOURCE address so DMA dest stays linear; fragment ds_read_b128 lands 2-way (free).
// mode 4 (fused QKV): A=[4096,1024], BT=[3072,1024]; col block 0->Q(x0.125) o0 [B,H,S,64],
//   1->K o1 [B,H,S,64], 2->V o2 [B,H,64,S] (transposed). biases selected by colb>>10.
// mode 3: O-proj, fp32 out o0 [4096,1024] + bias0.
__global__ __launch_bounds__(256) void gemm128(const u16* __restrict__ A, const u16* __restrict__ BT,
                                               const float* __restrict__ bias0, const float* __restrict__ bias1,
                                               const float* __restrict__ bias2,
                                               void* __restrict__ o0, void* __restrict__ o1, void* __restrict__ o2,
                                               int mode) {
  __shared__ __align__(16) u16 Als[128 * 64];  // 16 KB
  __shared__ __align__(16) u16 Bls[128 * 64];  // 16 KB
  const int m0 = blockIdx.x * 128, n0 = blockIdx.y * 128;
  const int lane = threadIdx.x & 63, wave = threadIdx.x >> 6;
  const int quad = lane >> 4, c = lane & 15;
  const int wm = wave >> 1, wn = wave & 1;

  // staging: call q stages rows wave*32+q*8 .. +7 (8 rows x 8 chunks = 64 lanes)
  const int srow = lane >> 3, schunk = lane & 7;
  int soff[4];  u16 *lA[4], *lB[4];
  #pragma unroll
  for (int q = 0; q < 4; ++q) {
    int r = wave * 32 + q * 8 + srow;
    soff[q] = r * 1024 + ((schunk ^ (r & 7)) << 3);
    lA[q] = &Als[(wave * 32 + q * 8) * 64 + lane * 8];
    lB[q] = &Bls[(wave * 32 + q * 8) * 64 + lane * 8];
  }
  const u16* gA = A + (size_t)m0 * 1024;
  const u16* gB = BT + (size_t)n0 * 1024;

  int ar[2][4], br[2][4];
  #pragma unroll
  for (int ko = 0; ko < 2; ++ko) {
    #pragma unroll
    for (int i = 0; i < 4; ++i) {
      int rowa = wm * 64 + i * 16 + c;
      ar[ko][i] = rowa * 64 + (((ko * 4 + quad) ^ (rowa & 7)) << 3);
      int rowb = wn * 64 + i * 16 + c;
      br[ko][i] = rowb * 64 + (((ko * 4 + quad) ^ (rowb & 7)) << 3);
    }
  }

  float4_t acc[4][4] = {};
  for (int k0 = 0; k0 < 1024; k0 += 64) {
    #pragma unroll
    for (int q = 0; q < 4; ++q) async16(gA + soff[q] + k0, lA[q]);
    #pragma unroll
    for (int q = 0; q < 4; ++q) async16(gB + soff[q] + k0, lB[q]);
    __syncthreads();
    #pragma unroll
    for (int ko = 0; ko < 2; ++ko) {
      short8_t af[4], bfr[4];
      #pragma unroll
      for (int i = 0; i < 4; ++i) af[i] = *(const short8_t*)&Als[ar[ko][i]];
      #pragma unroll
      for (int j = 0; j < 4; ++j) bfr[j] = *(const short8_t*)&Bls[br[ko][j]];
      #pragma unroll
      for (int i = 0; i < 4; ++i)
        #pragma unroll
        for (int j = 0; j < 4; ++j)
          acc[i][j] = __builtin_amdgcn_mfma_f32_16x16x32_bf16(af[i], bfr[j], acc[i][j], 0, 0, 0);
    }
    __syncthreads();
  }

  const int mrow = m0 + wm * 64, ncol = n0 + wn * 64;
  if (mode == 3) {
    float* o = (float*)o0;
    #pragma unroll
    for (int i = 0; i < 4; ++i) {
      #pragma unroll
      for (int j = 0; j < 4; ++j) {
        int colb = ncol + j * 16 + c;
        float bv = bias0[colb];
        int rowb = mrow + i * 16 + quad * 4;
        #pragma unroll
        for (int r = 0; r < 4; ++r)
          o[(size_t)(rowb + r) * 1024 + colb] = acc[i][j][r] + bv;
      }
    }
  } else {
    #pragma unroll
    for (int j = 0; j < 4; ++j) {
      int colb = ncol + j * 16 + c;     // 0..3071
      int which = colb >> 10;           // 0:Q 1:K 2:V (uniform per j)
      int n1 = colb & 1023, h = n1 >> 6, d = n1 & 63;
      const float* bp = (which == 0) ? bias0 : (which == 1 ? bias1 : bias2);
      float bv = bp[n1];
      #pragma unroll
      for (int i = 0; i < 4; ++i) {
        int rowb = mrow + i * 16 + quad * 4;
        int b = rowb >> 11, s = rowb & 2047;
        if (which == 2) {
          u16* o = (u16*)o2 + (((size_t)(b * 16 + h) * 64 + d) * 2048 + s);
          union { u32 u[2]; u64 ll; } ov;
          ov.u[0] = packbf(acc[i][j][0] + bv, acc[i][j][1] + bv);
          ov.u[1] = packbf(acc[i][j][2] + bv, acc[i][j][3] + bv);
          *(u64*)o = ov.ll;
        } else {
          float sc = (which == 0) ? 0.125f : 1.0f;
          u16* o = (u16*)((which == 0) ? o0 : o1);
          #pragma unroll
          for (int r = 0; r < 4; ++r)
            o[(((size_t)(b * 16 + h) * 2048 + (s + r)) << 6) + d] = f2bf((acc[i][j][r] + bv) * sc);
        }
      }
    }
  }
}

// ---------- softmax half: S^T fragment -> P^T B-operand fragment (fixed-base exp) ----------
__device__ inline short8_t half_softmax(float4_t s0, float4_t s1, float4_t mpl0, float4_t mpl1,
                                        bool diag, int kbase, int quad, int c, int qg, float& lacc) {
  const float LOG2E = 1.4426950408889634f;
  float p[8];
  #pragma unroll
  for (int e = 0; e < 8; ++e) {
    float sv = (e < 4) ? s0[e] : s1[e - 4];
    float ml = (e < 4) ? mpl0[e] : mpl1[e - 4];
    float arg = __builtin_fmaf(sv, LOG2E, ml);
    if (diag) {
      int kpos = kbase + ((e >> 2) << 4) + quad * 4 + (e & 3);
      arg = (kpos > qg) ? -50.0f : arg;   // exp2(-50) ~ 9e-16 ~ 0
    }
    float pe = exp2f(arg);
    p[e] = pe;
    lacc += pe;
  }
  u32 pk0[2] = {packbf(p[0], p[1]), packbf(p[2], p[3])};
  u32 pk1[2] = {packbf(p[4], p[5]), packbf(p[6], p[7])};
  int base = ((quad & 1) * 2) * 16 + c;
  union { u32 u[4]; short8_t v; } pf;
  #pragma unroll
  for (int x = 0; x < 4; ++x) {
    int src = base + ((x >> 1) << 4);
    int v0 = __shfl((int)pk0[x & 1], src);
    int v1 = __shfl((int)pk1[x & 1], src);
    pf.u[x] = (quad < 2) ? (u32)v0 : (u32)v1;
  }
  return pf.v;
}

// ---------- flash attention, one (bh, 32-query unit) per block, 4-way K-split ----------
// Q,K: [B,H,S,64] bf16 (Q pre-scaled 1/8); VT: [B,H,64,S]; ctx: [B,S,1024] bf16.
// Grid 2048: xcd = g&7 pins bh group (4 bh per XCD -> K/V L2-resident); u = 63-(g>>3>>2)
// dispatches heavy units first. 4 waves split K strided-by-4 (fixed-base softmax ->
// partials additively combinable); combine through 19KB LDS (A then B halves).
__global__ __launch_bounds__(256) void attn_kernel(const u16* __restrict__ Q, const u16* __restrict__ K,
                                                   const u16* __restrict__ VT, const float* __restrict__ mask,
                                                   u16* __restrict__ ctx) {
  __shared__ float cmb[4][64][19];
  const float C1 = 10000.0f * 1.4426950408889634f;
  int w = threadIdx.x >> 6, lane = threadIdx.x & 63;
  int quad = lane >> 4, c = lane & 15;
  int g = blockIdx.x;
  int xcd = g & 7, j = g >> 3;
  int bh = xcd * 4 + (j & 3);
  int u = 63 - (j >> 2);          // heavy first
  int b = bh >> 4, h = bh & 15;
  const u16* Kp = K + ((size_t)bh << 17);
  const u16* Vp = VT + ((size_t)bh << 17);
  const float* mp = mask + (b << 11);

  int q0 = u << 5;
  const u16* Qp = Q + (((size_t)bh * 2048 + q0 + c) << 6) + quad * 8;
  short8_t qA0 = *(const short8_t*)(Qp);
  short8_t qA1 = *(const short8_t*)(Qp + 32);
  short8_t qB0 = *(const short8_t*)(Qp + 1024);
  short8_t qB1 = *(const short8_t*)(Qp + 1024 + 32);
  float4_t OA[4] = {}, OB[4] = {};
  float lA = 0.0f, lB = 0.0f;
  int qgA = q0 + c, qgB = q0 + 16 + c;
  for (int t = w; t <= u; t += 4) {
    int kbase = t << 5;
    const u16* kp = Kp + (((size_t)kbase + c) << 6) + quad * 8;
    short8_t ka0 = *(const short8_t*)(kp);
    short8_t ka1 = *(const short8_t*)(kp + 32);
    short8_t kb0 = *(const short8_t*)(kp + 1024);
    short8_t kb1 = *(const short8_t*)(kp + 1024 + 32);
    const u16* vp = Vp + (size_t)c * 2048 + kbase + quad * 8;
    short8_t vf0 = *(const short8_t*)(vp);
    short8_t vf1 = *(const short8_t*)(vp + 16 * 2048);
    short8_t vf2 = *(const short8_t*)(vp + 32 * 2048);
    short8_t vf3 = *(const short8_t*)(vp + 48 * 2048);
    float4_t mv0 = *(const float4_t*)(mp + kbase + quad * 4);
    float4_t mv1 = *(const float4_t*)(mp + kbase + 16 + quad * 4);
    float4_t mpl0 = (mv0 - 1.0f) * C1;  // (1-m)*-10000*log2e
    float4_t mpl1 = (mv1 - 1.0f) * C1;
    bool diag = (t == u);
    float4_t sA0 = {}, sA1 = {}, sB0 = {}, sB1 = {};
    sA0 = __builtin_amdgcn_mfma_f32_16x16x32_bf16(ka0, qA0, sA0, 0, 0, 0);
    sA0 = __builtin_amdgcn_mfma_f32_16x16x32_bf16(ka1, qA1, sA0, 0, 0, 0);
    sA1 = __builtin_amdgcn_mfma_f32_16x16x32_bf16(kb0, qA0, sA1, 0, 0, 0);
    sA1 = __builtin_amdgcn_mfma_f32_16x16x32_bf16(kb1, qA1, sA1, 0, 0, 0);
    sB0 = __builtin_amdgcn_mfma_f32_16x16x32_bf16(ka0, qB0, sB0, 0, 0, 0);
    sB0 = __builtin_amdgcn_mfma_f32_16x16x32_bf16(ka1, qB1, sB0, 0, 0, 0);
    sB1 = __builtin_amdgcn_mfma_f32_16x16x32_bf16(kb0, qB0, sB1, 0, 0, 0);
    sB1 = __builtin_amdgcn_mfma_f32_16x16x32_bf16(kb1, qB1, sB1, 0, 0, 0);
    short8_t pfA = half_softmax(sA0, sA1, mpl0, mpl1, diag, kbase, quad, c, qgA, lA);
    short8_t pfB = half_softmax(sB0, sB1, mpl0, mpl1, diag, kbase, quad, c, qgB, lB);
    OA[0] = __builtin_amdgcn_mfma_f32_16x16x32_bf16(vf0, pfA, OA[0], 0, 0, 0);
    OA[1] = __builtin_amdgcn_mfma_f32_16x16x32_bf16(vf1, pfA, OA[1], 0, 0, 0);
    OA[2] = __builtin_amdgcn_mfma_f32_16x16x32_bf16(vf2, pfA, OA[2], 0, 0, 0);
    OA[3] = __builtin_amdgcn_mfma_f32_16x16x32_bf16(vf3, pfA, OA[3], 0, 0, 0);
    OB[0] = __builtin_amdgcn_mfma_f32_16x16x32_bf16(vf0, pfB, OB[0], 0, 0, 0);
    OB[1] = __builtin_amdgcn_mfma_f32_16x16x32_bf16(vf1, pfB, OB[1], 0, 0, 0);
    OB[2] = __builtin_amdgcn_mfma_f32_16x16x32_bf16(vf2, pfB, OB[2], 0, 0, 0);
    OB[3] = __builtin_amdgcn_mfma_f32_16x16x32_bf16(vf3, pfB, OB[3], 0, 0, 0);
  }
  // ---- combine half A ----
  float* cw = &cmb[w][lane][0];
  #pragma unroll
  for (int d = 0; d < 4; ++d)
    #pragma unroll
    for (int r = 0; r < 4; ++r) cw[d * 4 + r] = OA[d][r];
  cw[16] = lA;
  __syncthreads();
  {
    float4_t sA = {};
    float la = 0.0f;
    #pragma unroll
    for (int w2 = 0; w2 < 4; ++w2) {
      const float* cr = &cmb[w2][lane][0];
      #pragma unroll
      for (int r = 0; r < 4; ++r) sA[r] += cr[w * 4 + r];
      la += cr[16];
    }
    la += __shfl_xor(la, 16); la += __shfl_xor(la, 32);
    float rA = 1.0f / la;
    u16* opA = ctx + ((size_t)(b * 2048 + q0 + c) * 1024 + h * 64 + w * 16 + quad * 4);
    union { u32 uu[2]; u64 ll; } ov;
    ov.uu[0] = packbf(sA[0] * rA, sA[1] * rA);
    ov.uu[1] = packbf(sA[2] * rA, sA[3] * rA);
    *(u64*)opA = ov.ll;
  }
  __syncthreads();
  // ---- combine half B ----
  #pragma unroll
  for (int d = 0; d < 4; ++d)
    #pragma unroll
    for (int r = 0; r < 4; ++r) cw[d * 4 + r] = OB[d][r];
  cw[16] = lB;
  __syncthreads();
  {
    float4_t sB = {};
    float lb = 0.0f;
    #pragma unroll
    for (int w2 = 0; w2 < 4; ++w2) {
      const float* cr = &cmb[w2][lane][0];
      #pragma unroll
      for (int r = 0; r < 4; ++r) sB[r] += cr[w * 4 + r];
      lb += cr[16];
    }
    lb += __shfl_xor(lb, 16); lb += __shfl_xor(lb, 32);
    float rB = 1.0f / lb;
    u16* opB = ctx + ((size_t)(b * 2048 + q0 + 16 + c) * 1024 + h * 64 + w * 16 + quad * 4);
    union { u32 uu[2]; u64 ll; } ov;
    ov.uu[0] = packbf(sB[0] * rB, sB[1] * rB);
    ov.uu[1] = packbf(sB[2] * rB, sB[3] * rB);
    *(u64*)opB = ov.ll;
  }
}

// ---------- launch ----------
extern "C" void kernel_launch(void* const* d_in, const int* in_sizes, int n_in,
                              void* d_out, int out_size, void* d_ws, size_t ws_size,
                              hipStream_t stream) {
  const float* X    = (const float*)d_in[0];
  const float* mask = (const float*)d_in[1];
  const float* Wq   = (const float*)d_in[2];
  const float* bq   = (const float*)d_in[3];
  const float* Wk   = (const float*)d_in[4];
  const float* bk   = (const float*)d_in[5];
  const float* Wv   = (const float*)d_in[6];
  const float* bv   = (const float*)d_in[7];
  const float* Wo   = (const float*)d_in[8];
  const float* bo   = (const float*)d_in[9];

  char* w = (char*)d_ws;
  u16* Xb     = (u16*)(w);                 // 8 MB  [4096,1024] bf16
  u16* WqkvT  = (u16*)(w + (8ull  << 20)); // 6 MB  [3072,1024] bf16 (Q|K|V transposed)
  u16* WoT    = (u16*)(w + (14ull << 20)); // 2 MB  [1024,1024] bf16
  u16* Qb     = (u16*)(w + (16ull << 20)); // 8 MB [B,H,S,64]
  u16* Kb     = (u16*)(w + (24ull << 20)); // 8 MB [B,H,S,64]
  u16* VTb    = (u16*)(w + (32ull << 20)); // 8 MB [B,H,64,S]
  u16* Ctx    = (u16*)(w + (40ull << 20)); // 8 MB [4096,1024]

  prologue<<<8192, 256, 0, stream>>>(X, Wq, Wk, Wv, Wo, Xb, WqkvT, WoT);
  gemm128<<<dim3(32, 24), 256, 0, stream>>>(Xb, WqkvT, bq, bk, bv, Qb, Kb, VTb, 4);
  attn_kernel<<<2048, 256, 0, stream>>>(Qb, Kb, VTb, mask, Ctx);
  gemm128<<<dim3(32, 8), 256, 0, stream>>>(Ctx, WoT, bo, bo, bo, d_out, d_out, d_out, 3);
}